// Round 2
// baseline (1539.281 us; speedup 1.0000x reference)
//
#include <hip/hip_runtime.h>

typedef float f32x2 __attribute__((ext_vector_type(2)));
typedef float f32x4 __attribute__((ext_vector_type(4)));

#define BB 256
#define TT 1024
#define HH 128
#define CC 2

// tanh(u) = 1 - 2/(exp(2u)+1); branchless. Validated in prior session: absmax 9.77e-4.
__device__ __forceinline__ float ftanh(float u) {
    float e = __expf(2.0f * u);
    float r = __builtin_amdgcn_rcpf(e + 1.0f);
    return fmaf(-2.0f, r, 1.0f);
}

// component-wise fma on float2 -> should select v_pk_fma_f32 (packed fp32 pipe)
__device__ __forceinline__ f32x2 pkfma(f32x2 a, f32x2 b, f32x2 c) {
    return (f32x2){fmaf(a.x, b.x, c.x), fmaf(a.y, b.y, c.y)};
}

// One wave per batch element. Lane l owns output rows l and l+64 over FULL K=128.
// No __syncthreads in the recurrence loop: h flows through a same-wave LDS ring
// (DS pipe is in-order per wave; compiler inserts lgkmcnt for the may-alias reads).
__global__ __launch_bounds__(64, 1) void rnn_kernel(
    const float* __restrict__ x, const float* __restrict__ W_ih,
    const float* __restrict__ W_hh, const float* __restrict__ b_ih,
    const float* __restrict__ b_hh, const float* __restrict__ W_fc,
    const float* __restrict__ b_fc, float* __restrict__ out)
{
    const int b = blockIdx.x;     // 0..255
    const int l = threadIdx.x;    // 0..63

    __shared__ float xs[TT + 4];        // input sequence (+pad for prefetch)
    __shared__ float hring[16][132];    // h history ring; stride 132 breaks bank alias

    // preload x row (64 lanes x 4 x f32x4, coalesced)
    {
        const f32x4* xr = (const f32x4*)(x + (size_t)b * TT);
        f32x4* xd = (f32x4*)xs;
        #pragma unroll
        for (int i = 0; i < 4; ++i) xd[i * 64 + l] = xr[i * 64 + l];
    }
    if (l < 4) xs[TT + l] = 0.f;
    // h_{-1} = 0 lives in slot 15
    hring[15][l] = 0.f;
    hring[15][l + 64] = 0.f;

    // per-lane weights: rows l and l+64, k-pair packed -> 128 f32x2 = 256 VGPRs.
    // Pinned in VGPRs (compiler otherwise re-fetches from L1 per step).
    f32x2 wA[64], wB[64];
    {
        const f32x2* a2 = (const f32x2*)(W_hh + (size_t)l * HH);
        const f32x2* b2 = (const f32x2*)(W_hh + (size_t)(l + 64) * HH);
        #pragma unroll
        for (int j = 0; j < 64; ++j) { wA[j] = a2[j]; wB[j] = b2[j]; }
        #pragma unroll
        for (int j = 0; j < 64; ++j)
            asm volatile("" : "+v"(wA[j]), "+v"(wB[j]));
    }

    const f32x2 wih2  = (f32x2){W_ih[l], W_ih[l + 64]};
    const f32x2 bias2 = (f32x2){b_ih[l] + b_hh[l], b_ih[l + 64] + b_hh[l + 64]};

    // batched-logit lane mapping: class = l&1, time-slot = (l>>1)&15, k-half = l>>5
    const int lc = l & 1;
    const int lt = (l >> 1) & 15;
    const int lh = l >> 5;
    const f32x4* wf4 = (const f32x4*)(W_fc + lc * HH + lh * 64);
    const float bfc = b_fc[lc];
    float* o = out + (size_t)b * TT * CC;

    __syncthreads();   // one-time: xs + ring-slot-15 visible across lanes

    float xcur = xs[0];

    for (int t = 0; t < TT; ++t) {
        // ---- matvec: read h_{t-1} (broadcast b128 reads, conflict-free),
        // chase with packed FMAs against register-resident weights.
        const f32x4* h4 = (const f32x4*)hring[(t + 15) & 15];

        f32x2 aA0 = (f32x2){0.f, 0.f}, aA1 = aA0, aB0 = aA0, aB1 = aA0;
        #pragma unroll
        for (int j = 0; j < 32; ++j) {
            const f32x4 hv = h4[j];
            const f32x2 hlo = (f32x2){hv.x, hv.y};
            const f32x2 hhi = (f32x2){hv.z, hv.w};
            aA0 = pkfma(wA[2 * j],     hlo, aA0);
            aA1 = pkfma(wA[2 * j + 1], hhi, aA1);
            aB0 = pkfma(wB[2 * j],     hlo, aB0);
            aB1 = pkfma(wB[2 * j + 1], hhi, aB1);
        }

        const float xnext = xs[t + 1];                       // prefetch
        const f32x2 base = pkfma((f32x2){xcur, xcur}, wih2, bias2);
        xcur = xnext;

        const float sA = (aA0.x + aA0.y) + (aA1.x + aA1.y);
        const float sB = (aB0.x + aB0.y) + (aB1.x + aB1.y);
        const float hA = ftanh(base.x + sA);
        const float hB = ftanh(base.y + sB);

        // publish h_t (same-wave LDS, in-order DS pipe -> no barrier)
        float* hw = hring[t & 15];
        hw[l] = hA;
        hw[l + 64] = hB;

        // ---- every 16 steps: batched logits for t-15..t from the ring.
        // Lane l: class lc, timestep (t-15+lt), k-half lh. One coalesced store.
        if ((t & 15) == 15) {
            const f32x4* hb = (const f32x4*)(&hring[lt][lh * 64]);
            f32x2 q0 = (f32x2){0.f, 0.f}, q1 = q0;
            #pragma unroll
            for (int j = 0; j < 16; ++j) {
                const f32x4 hv = hb[j];
                const f32x4 wv = wf4[j];
                q0 = pkfma((f32x2){wv.x, wv.y}, (f32x2){hv.x, hv.y}, q0);
                q1 = pkfma((f32x2){wv.z, wv.w}, (f32x2){hv.z, hv.w}, q1);
            }
            const f32x2 qs = q0 + q1;
            float q = qs.x + qs.y;
            q += __shfl_xor(q, 32);          // combine k-halves (l <-> l^32)
            if (l < 32) o[(t - 15) * CC + l] = q + bfc;   // 128B coalesced
        }
    }
}

extern "C" void kernel_launch(void* const* d_in, const int* in_sizes, int n_in,
                              void* d_out, int out_size, void* d_ws, size_t ws_size,
                              hipStream_t stream) {
    const float* x    = (const float*)d_in[0];
    const float* W_ih = (const float*)d_in[1];
    const float* W_hh = (const float*)d_in[2];
    const float* b_ih = (const float*)d_in[3];
    const float* b_hh = (const float*)d_in[4];
    const float* W_fc = (const float*)d_in[5];
    const float* b_fc = (const float*)d_in[6];
    float* out = (float*)d_out;

    rnn_kernel<<<BB, 64, 0, stream>>>(x, W_ih, W_hh, b_ih, b_hh, W_fc, b_fc, out);
}

// Round 3
// 447.437 us; speedup vs baseline: 3.4402x; 3.4402x over previous
//
#include <hip/hip_runtime.h>

typedef float f32x2 __attribute__((ext_vector_type(2)));
typedef float f32x4 __attribute__((ext_vector_type(4)));

#define BB 256
#define TT 1024
#define HH 128
#define CC 2

// tanh(u) = 1 - 2/(exp(2u)+1); branchless. Validated: absmax 9.77e-4.
__device__ __forceinline__ float ftanh(float u) {
    float e = __expf(2.0f * u);
    float r = __builtin_amdgcn_rcpf(e + 1.0f);
    return fmaf(-2.0f, r, 1.0f);
}

__device__ __forceinline__ f32x2 pkfma(f32x2 a, f32x2 b, f32x2 c) {
    return (f32x2){fmaf(a.x, b.x, c.x), fmaf(a.y, b.y, c.y)};
}

// 4 waves / block. Wave w owns rows [32w, 32w+32). Lane l6 (0..63):
//   row r = 32w + (l6 & 31), k-half kh = l6 >> 5 (k in [64*kh, 64*kh+64)).
// Per-lane weights: 64 floats = 32 f32x2 = 64 VGPRs -> fits the v0..v255 file
// (Round-2 lesson: 256 weight VGPRs/lane spills; 184-reg alloc, 3.7x slowdown).
// k-half combine is IN-WAVE (shfl_xor 32) -> no cross-wave partial round trip.
// One __syncthreads per step publishes h_t; 32-deep ring makes the every-16-step
// logit pass race-free without a second barrier.
__global__ __launch_bounds__(256, 1) void rnn_kernel(
    const float* __restrict__ x, const float* __restrict__ W_ih,
    const float* __restrict__ W_hh, const float* __restrict__ b_ih,
    const float* __restrict__ b_hh, const float* __restrict__ W_fc,
    const float* __restrict__ b_fc, float* __restrict__ out)
{
    const int b   = blockIdx.x;        // 0..255
    const int tid = threadIdx.x;       // 0..255
    const int w   = tid >> 6;          // wave 0..3
    const int l6  = tid & 63;
    const int r   = (w << 5) + (l6 & 31);  // row 0..127
    const int kb  = (l6 >> 5) << 6;        // k-base: 0 or 64

    __shared__ float xs[TT + 4];        // input sequence (+pad for prefetch)
    __shared__ float hring[32][132];    // 32-deep h ring; stride 132 spreads banks

    // preload x row (256 lanes x f32x4, coalesced)
    ((f32x4*)xs)[tid] = ((const f32x4*)(x + (size_t)b * TT))[tid];
    if (tid < 4) xs[TT + tid] = 0.f;
    if (tid < HH) hring[31][tid] = 0.f;    // h_{-1} = 0 in slot 31

    // per-lane weights: row r over k in [kb, kb+64) -> 32 f32x2, VGPR-resident
    f32x2 wv[32];
    {
        const f32x2* wrow = (const f32x2*)(W_hh + (size_t)r * HH + kb);
        #pragma unroll
        for (int j = 0; j < 32; ++j) wv[j] = wrow[j];
        #pragma unroll
        for (int j = 0; j < 32; ++j) asm volatile("" : "+v"(wv[j]));
    }

    const float wih  = W_ih[r];
    const float bias = b_ih[r] + b_hh[r];

    // batched-logit mapping: 32 outputs (16 t-slots x 2 classes), 8 lanes each.
    // Wave w covers t-slots 4w..4w+3. class = l6&1, slot-in-wave = (l6>>1)&3,
    // k-eighth = (l6>>3)&7 (16 floats each). Reduce over eighths: xor 8,16,32.
    const int lc  = l6 & 1;
    const int lsi = (l6 >> 1) & 3;
    const int le  = (l6 >> 3) & 7;
    const f32x4* wf4 = (const f32x4*)(W_fc + lc * HH + le * 16);
    const float bfc = b_fc[lc];
    float* o = out + (size_t)b * TT * CC;

    __syncthreads();   // xs + ring slot 31 visible
    float xcur = xs[0];

    for (int t = 0; t < TT; ++t) {
        // ---- matvec half-row: 16 uniform ds_read_b128 (broadcast, conflict-
        // free; the two k-half addresses are a benign 2-way bank alias) feeding
        // 32 pk_fma against VGPR-resident weights, 8 interleaved accumulators.
        const f32x4* h4 = (const f32x4*)(&hring[(t + 31) & 31][kb]);

        f32x2 a0 = (f32x2){0.f, 0.f}, a1 = a0, a2 = a0, a3 = a0;
        f32x2 a4 = a0, a5 = a0, a6 = a0, a7 = a0;
        #pragma unroll
        for (int j = 0; j < 4; ++j) {
            const f32x4 h0 = h4[4 * j + 0];
            const f32x4 h1 = h4[4 * j + 1];
            const f32x4 h2 = h4[4 * j + 2];
            const f32x4 h3 = h4[4 * j + 3];
            a0 = pkfma(wv[8 * j + 0], (f32x2){h0.x, h0.y}, a0);
            a1 = pkfma(wv[8 * j + 1], (f32x2){h0.z, h0.w}, a1);
            a2 = pkfma(wv[8 * j + 2], (f32x2){h1.x, h1.y}, a2);
            a3 = pkfma(wv[8 * j + 3], (f32x2){h1.z, h1.w}, a3);
            a4 = pkfma(wv[8 * j + 4], (f32x2){h2.x, h2.y}, a4);
            a5 = pkfma(wv[8 * j + 5], (f32x2){h2.z, h2.w}, a5);
            a6 = pkfma(wv[8 * j + 6], (f32x2){h3.x, h3.y}, a6);
            a7 = pkfma(wv[8 * j + 7], (f32x2){h3.z, h3.w}, a7);
        }

        const float xnext = xs[t + 1];                 // prefetch (pad-safe)
        const float base  = fmaf(xcur, wih, bias);
        xcur = xnext;

        // reduce 8 accumulators -> scalar half-row sum
        const f32x2 s0 = a0 + a1, s1 = a2 + a3, s2 = a4 + a5, s3 = a6 + a7;
        const f32x2 sv = (s0 + s1) + (s2 + s3);
        float s = sv.x + sv.y;
        // combine k-halves in-wave (lane l6 <-> l6^32 share row r)
        s += __shfl_xor(s, 32);

        const float hn = ftanh(base + s);

        // publish h_t (kh=0 lanes only; one writer per row, conflict-free)
        if (l6 < 32) hring[t & 31][r] = hn;
        __syncthreads();

        // ---- every 16 steps: batched logits for timesteps t-15..t
        if ((t & 15) == 15) {
            const int u = t - 15 + 4 * w + lsi;        // absolute timestep
            const f32x4* hb = (const f32x4*)(&hring[u & 31][le * 16]);
            f32x2 q0 = (f32x2){0.f, 0.f}, q1 = q0;
            #pragma unroll
            for (int j = 0; j < 4; ++j) {
                const f32x4 hv = hb[j];
                const f32x4 wl = wf4[j];
                q0 = pkfma((f32x2){wl.x, wl.y}, (f32x2){hv.x, hv.y}, q0);
                q1 = pkfma((f32x2){wl.z, wl.w}, (f32x2){hv.z, hv.w}, q1);
            }
            const f32x2 qq = q0 + q1;
            float qs = qq.x + qq.y;
            qs += __shfl_xor(qs, 8);
            qs += __shfl_xor(qs, 16);
            qs += __shfl_xor(qs, 32);
            if (l6 < 8) o[(t - 15) * CC + 8 * w + l6] = qs + bfc;
        }
    }
}

extern "C" void kernel_launch(void* const* d_in, const int* in_sizes, int n_in,
                              void* d_out, int out_size, void* d_ws, size_t ws_size,
                              hipStream_t stream) {
    const float* x    = (const float*)d_in[0];
    const float* W_ih = (const float*)d_in[1];
    const float* W_hh = (const float*)d_in[2];
    const float* b_ih = (const float*)d_in[3];
    const float* b_hh = (const float*)d_in[4];
    const float* W_fc = (const float*)d_in[5];
    const float* b_fc = (const float*)d_in[6];
    float* out = (float*)d_out;

    rnn_kernel<<<BB, 256, 0, stream>>>(x, W_ih, W_hh, b_ih, b_hh, W_fc, b_fc, out);
}